// Round 15
// baseline (184.108 us; speedup 1.0000x reference)
//
#include <hip/hip_runtime.h>
#include <hip/hip_fp16.h>

#define NN 50000
#define NE 1600000
#define NPB 32                       // nodes per bin
#define NBIN ((NN + NPB - 1) / NPB)  // 1563 (last bin: 16 valid nodes)
#define NXCD 8
#define WBLK 512                     // cnt / binwrite chunk blocks
#define EPB (NE / WBLK)              // 3125 edges per chunk
#define CAP 2048                     // staged records per bin (mean 1024, max ~1170)

// ---------------- workspace layout ----------------
// er[NE] float2 {src|(dl<<16), ew}, ordered by (bin, xcd)        12.8 MB
// dinv[NN]
// gbincnt8[8*NBIN] u32 (zeroed in k_prep0) : per-(xcd,bin) record counts
// binstart[NBIN+1] u32                     : per-bin global ranges
// bincur8[8*NBIN] u32                      : per-(xcd,bin) write cursors
// Mz[1024] | Mh[1024] | cz[32] | ch[32]
// xh[NN*16] half2 (3.2 MB)                 : fp16 copy of x for the gather

// Zero counters + convert x -> fp16 rows (halves the gather bytes).
__global__ __launch_bounds__(1024) void k_prep0(const float* __restrict__ x,
                                                unsigned* __restrict__ gbincnt8,
                                                __half2* __restrict__ xh) {
    int i = blockIdx.x * 1024 + threadIdx.x;
    if (i < NXCD * NBIN) gbincnt8[i] = 0u;
    if (i < NN * 16) {
        float2 v = ((const float2*)x)[i];
        xh[i] = __floats2half2_rn(v.x, v.y);
    }
}

// Per-(xcd,bin) edge counts: LDS histogram per chunk, dense coalesced flush
// into this block's XCD row.
__global__ __launch_bounds__(256) void k_cnt(const int* __restrict__ ei,
                                             unsigned* __restrict__ gbincnt8) {
    __shared__ unsigned cnt[NBIN];
    int t = threadIdx.x;
    int xcd = blockIdx.x & (NXCD - 1);
    for (int i = t; i < NBIN; i += 256) cnt[i] = 0u;
    __syncthreads();
    int lo = blockIdx.x * EPB, hi = lo + EPB;
    for (int e = lo + t; e < hi; e += 256)
        atomicAdd(&cnt[ei[NE + e] >> 5], 1u);              // LDS
    __syncthreads();
    for (int i = t; i < NBIN; i += 256)
        if (cnt[i]) atomicAdd(&gbincnt8[xcd * NBIN + i], cnt[i]);  // coalesced
}

// b==0: scan per-(xcd,bin) counts -> binstart (bin-contiguous) + bincur8
//       (xcd sub-offsets within each bin).
// b==1: fold weights: Mz = Wz@Lzw[:32,:], cz = bz@Lzw + Lzb; same for h.
//       (H0 = 0 kills the R gate and the bottom halves of the gate linears.)
__global__ __launch_bounds__(256) void k_mid(
        const unsigned* __restrict__ gbincnt8, unsigned* __restrict__ binstart,
        unsigned* __restrict__ bincur8,
        const float* __restrict__ Wz, const float* __restrict__ Lzw,
        const float* __restrict__ bz, const float* __restrict__ Lzb,
        const float* __restrict__ Wh, const float* __restrict__ Lhw,
        const float* __restrict__ bh, const float* __restrict__ Lhb,
        float* __restrict__ Mz, float* __restrict__ Mh,
        float* __restrict__ cz, float* __restrict__ chv) {
    int t = threadIdx.x;
    if (blockIdx.x == 0) {
        __shared__ unsigned ts[256];
        unsigned s = 0;
#pragma unroll
        for (int r = 0; r < 7; ++r) {
            int idx = t * 7 + r;
            if (idx < NBIN)
                for (int x = 0; x < NXCD; ++x) s += gbincnt8[x * NBIN + idx];
        }
        ts[t] = s;
        __syncthreads();
        for (int off = 1; off < 256; off <<= 1) {
            unsigned u = (t >= off) ? ts[t - off] : 0u;
            __syncthreads();
            ts[t] += u;
            __syncthreads();
        }
        unsigned acc = (t > 0) ? ts[t - 1] : 0u;
#pragma unroll
        for (int r = 0; r < 7; ++r) {
            int idx = t * 7 + r;
            if (idx < NBIN) {
                binstart[idx] = acc;
                for (int x = 0; x < NXCD; ++x) {
                    bincur8[x * NBIN + idx] = acc;
                    acc += gbincnt8[x * NBIN + idx];
                }
            }
        }
        if (t == 255) binstart[NBIN] = NE;
    } else {
#pragma unroll
        for (int r = 0; r < 4; ++r) {
            int t2 = r * 256 + t;
            int i = t2 >> 5, j = t2 & 31;
            float sz = 0.f, sh = 0.f;
            for (int k = 0; k < 32; ++k) {
                sz += Wz[i * 32 + k] * Lzw[k * 32 + j];
                sh += Wh[i * 32 + k] * Lhw[k * 32 + j];
            }
            Mz[t2] = sz;
            Mh[t2] = sh;
        }
        if (t < 32) {
            float az = Lzb[t], ah = Lhb[t];
            for (int k = 0; k < 32; ++k) {
                az += bz[k] * Lzw[k * 32 + t];
                ah += bh[k] * Lhw[k * 32 + t];
            }
            cz[t] = az;
            chv[t] = ah;
        }
    }
}

// Bin edges by dst into XCD-private sub-ranges: LDS count -> coalesced
// reservation on this XCD's cursor row -> scatter records {src|dl<<16, ew}.
// All stores to any er cache line come from ONE XCD -> full-line write-back.
__global__ __launch_bounds__(256) void k_binwrite(const int* __restrict__ ei,
                                                  const float* __restrict__ ew,
                                                  unsigned* __restrict__ bincur8,
                                                  float2* __restrict__ er) {
    __shared__ unsigned cnt[NBIN], base[NBIN];
    int t = threadIdx.x;
    int xcd = blockIdx.x & (NXCD - 1);
    for (int i = t; i < NBIN; i += 256) cnt[i] = 0u;
    __syncthreads();
    int lo = blockIdx.x * EPB, hi = lo + EPB;
    for (int e = lo + t; e < hi; e += 256)
        atomicAdd(&cnt[ei[NE + e] >> 5], 1u);              // LDS
    __syncthreads();
    for (int i = t; i < NBIN; i += 256)
        base[i] = cnt[i] ? atomicAdd(&bincur8[xcd * NBIN + i], cnt[i]) : 0u;
    __syncthreads();
    for (int e = lo + t; e < hi; e += 256) {
        int s = ei[e], d = ei[NE + e];
        unsigned idx = atomicAdd(&base[d >> 5], 1u);       // LDS cursor
        er[idx] = make_float2(
            __uint_as_float((unsigned)s | ((unsigned)(d & 31) << 16)), ew[e]);
    }
}

// Per-bin in-weight sums from the binned records -> dinv (dense write).
__global__ __launch_bounds__(256) void k_deg(const float2* __restrict__ er,
                                             const unsigned* __restrict__ binstart,
                                             float* __restrict__ dinv) {
    __shared__ float degL[NPB];
    int t = threadIdx.x;
    if (t < NPB) degL[t] = 0.f;
    __syncthreads();
    unsigned beg = binstart[blockIdx.x], end = binstart[blockIdx.x + 1];
    for (unsigned i = beg + t; i < end; i += 256) {
        float2 r = er[i];
        atomicAdd(&degL[(__float_as_uint(r.x) >> 16) & 31u], r.y);  // LDS
    }
    __syncthreads();
    if (t < NPB) {
        int n = blockIdx.x * NPB + t;
        if (n < NN) dinv[n] = rsqrtf(degL[t] + 1.0f);  // +1 = self-loop
    }
}

// One block (256 thr) per bin: r10's k_accum verbatim through the owner loop,
// then the dense epilogue runs in-block on an LDS overlay of the sort buffer
// (r13 proved phase-overlay safety). A never touches global memory; k_dense
// and the 12.8 MB Aout round-trip are deleted.
__global__ __launch_bounds__(256) void k_fused(
        const float2* __restrict__ er, const unsigned* __restrict__ binstart,
        const float* __restrict__ dinv, const float* __restrict__ x,
        const __half2* __restrict__ xh,
        const float* __restrict__ Mz, const float* __restrict__ Mh,
        const float* __restrict__ cz, const float* __restrict__ chv,
        const float* __restrict__ Wout, const float* __restrict__ bout,
        float* __restrict__ out) {
    __shared__ union {
        float2 srt[CAP];                 // 16384 B (sort phase)
        struct {                         // 14784 B (dense phase)
            float A[NPB][33];
            float sMz[1024], sMh[1024], sW[512];
            float scz[32], sch[32], sb[16];
        } d;
    } U;
    __shared__ unsigned cnt4[4][32];     // per-wave hist
    __shared__ unsigned base4[4][32];    // scatter cursors
    __shared__ unsigned rowp[33];
    const float4* x4 = (const float4*)x;
    const uint2* xh2 = (const uint2*)xh;  // 4 halves per uint2; 8 per row
    int t = threadIdx.x;
    int w = t >> 6;
    unsigned beg = binstart[blockIdx.x], end = binstart[blockIdx.x + 1];
    unsigned cntb = end - beg;
    unsigned stage = cntb < CAP ? cntb : CAP;

    if (t < 128) ((unsigned*)cnt4)[t] = 0u;
    __syncthreads();

    // stage up to 8 records/thread (weight premultiplied by dinv[src]) + hist
    float2 rec[8];
    unsigned dlk[8];
    bool val[8];
#pragma unroll
    for (int k = 0; k < 8; ++k) {
        unsigned i = (unsigned)t + (unsigned)k * 256u;
        val[k] = (i < stage);
        if (val[k]) {
            float2 r = er[beg + i];
            unsigned pk = __float_as_uint(r.x);
            r.y *= dinv[pk & 0xFFFFu];            // L2-hot 200KB broadcast
            rec[k] = r;
            unsigned d = (pk >> 16) & 31u;
            dlk[k] = d;
            atomicAdd(&cnt4[w][d], 1u);           // within-wave collisions only
        }
    }
    __syncthreads();

    // lanes 0..31 of wave 0: per-node totals, exclusive scan, per-wave bases
    if (t < 32) {
        unsigned s = 0;
#pragma unroll
        for (int ww = 0; ww < 4; ++ww) {
            unsigned c = cnt4[ww][t];
            base4[ww][t] = s;
            s += c;
        }
        unsigned tot = s;
#pragma unroll
        for (int off = 1; off < 32; off <<= 1) {
            unsigned v = __shfl_up(tot, off, 32);
            if (t >= off) tot += v;
        }
        unsigned excl = tot - s;
        rowp[t] = excl;
        if (t == 31) rowp[32] = excl + s;
#pragma unroll
        for (int ww = 0; ww < 4; ++ww) base4[ww][t] += excl;
    }
    __syncthreads();

    // scatter to sorted LDS
#pragma unroll
    for (int k = 0; k < 8; ++k) {
        if (val[k]) {
            unsigned p = atomicAdd(&base4[w][dlk[k]], 1u);
            U.srt[p] = rec[k];
        }
    }
    __syncthreads();

    // owner-computes: node l, 4-float slice j. Register accumulation; fp16
    // gathers (8B per record), fp32 math.
    int l = t >> 3, j = t & 7;
    int n = blockIdx.x * NPB + l;
    float4 acc = make_float4(0.f, 0.f, 0.f, 0.f);
    unsigned rb = rowp[l], re = rowp[l + 1];
    unsigned i = rb;
    for (; i + 4 <= re; i += 4) {
        float2 r0 = U.srt[i], r1 = U.srt[i + 1], r2 = U.srt[i + 2], r3 = U.srt[i + 3];
        unsigned s0 = __float_as_uint(r0.x) & 0xFFFFu;
        unsigned s1 = __float_as_uint(r1.x) & 0xFFFFu;
        unsigned s2 = __float_as_uint(r2.x) & 0xFFFFu;
        unsigned s3 = __float_as_uint(r3.x) & 0xFFFFu;
        uint2 v0 = xh2[s0 * 8 + j];
        uint2 v1 = xh2[s1 * 8 + j];
        uint2 v2 = xh2[s2 * 8 + j];
        uint2 v3 = xh2[s3 * 8 + j];
        float2 a0 = __half22float2(*(const __half2*)&v0.x);
        float2 b0 = __half22float2(*(const __half2*)&v0.y);
        float2 a1 = __half22float2(*(const __half2*)&v1.x);
        float2 b1 = __half22float2(*(const __half2*)&v1.y);
        float2 a2 = __half22float2(*(const __half2*)&v2.x);
        float2 b2 = __half22float2(*(const __half2*)&v2.y);
        float2 a3 = __half22float2(*(const __half2*)&v3.x);
        float2 b3 = __half22float2(*(const __half2*)&v3.y);
        acc.x += r0.y * a0.x; acc.y += r0.y * a0.y; acc.z += r0.y * b0.x; acc.w += r0.y * b0.y;
        acc.x += r1.y * a1.x; acc.y += r1.y * a1.y; acc.z += r1.y * b1.x; acc.w += r1.y * b1.y;
        acc.x += r2.y * a2.x; acc.y += r2.y * a2.y; acc.z += r2.y * b2.x; acc.w += r2.y * b2.y;
        acc.x += r3.y * a3.x; acc.y += r3.y * a3.y; acc.z += r3.y * b3.x; acc.w += r3.y * b3.y;
    }
    for (; i < re; ++i) {
        float2 r = U.srt[i];
        unsigned s = __float_as_uint(r.x) & 0xFFFFu;
        uint2 v = xh2[s * 8 + j];
        float2 a = __half22float2(*(const __half2*)&v.x);
        float2 b = __half22float2(*(const __half2*)&v.y);
        acc.x += r.y * a.x; acc.y += r.y * a.y; acc.z += r.y * b.x; acc.w += r.y * b.y;
    }
    // overflow fallback (never triggers for this input: max bin ~1170 < 2048);
    // reads global er, not srt.
    for (unsigned o = stage; o < cntb; ++o) {
        float2 r = er[beg + o];
        unsigned pk = __float_as_uint(r.x);
        if (((pk >> 16) & 31u) == (unsigned)l) {
            unsigned s = pk & 0xFFFFu;
            uint2 v = xh2[s * 8 + j];
            float2 a = __half22float2(*(const __half2*)&v.x);
            float2 b = __half22float2(*(const __half2*)&v.y);
            float vv = r.y * dinv[s];
            acc.x += vv * a.x; acc.y += vv * a.y; acc.z += vv * b.x; acc.w += vv * b.y;
        }
    }
    // self-loop term from fp32 x (exact): A = dv*(acc + dv*x_n); 0 for pad nodes
    float4 o4 = make_float4(0.f, 0.f, 0.f, 0.f);
    if (n < NN) {
        float dv = dinv[n];
        float4 xv = x4[n * 8 + j];
        o4.x = dv * (acc.x + dv * xv.x);
        o4.y = dv * (acc.y + dv * xv.y);
        o4.z = dv * (acc.z + dv * xv.z);
        o4.w = dv * (acc.w + dv * xv.w);
    }
    __syncthreads();                     // ALL reads of U.srt complete

    // ---- dense phase on the overlay (identical math to r10 k_dense) ----
    U.d.A[l][4 * j + 0] = o4.x;
    U.d.A[l][4 * j + 1] = o4.y;
    U.d.A[l][4 * j + 2] = o4.z;
    U.d.A[l][4 * j + 3] = o4.w;
    for (int i2 = t; i2 < 1024; i2 += 256) { U.d.sMz[i2] = Mz[i2]; U.d.sMh[i2] = Mh[i2]; }
    for (int i2 = t; i2 < 512; i2 += 256) U.d.sW[i2] = Wout[i2];
    if (t < 32) { U.d.scz[t] = cz[t]; U.d.sch[t] = chv[t]; }
    if (t < 16) U.d.sb[t] = bout[t];
    __syncthreads();

    // gates: 4 passes of 8 nodes (g = node-in-bin, f = feature)
    float hv[4];
#pragma unroll
    for (int ppp = 0; ppp < 4; ++ppp) {
        int g = (t >> 5) + ppp * 8, f = t & 31;
        float z = U.d.scz[f], gh = U.d.sch[f];
#pragma unroll
        for (int kk = 0; kk < 32; ++kk) {
            float ak = U.d.A[g][kk];       // broadcast within 32-lane group
            z += ak * U.d.sMz[kk * 32 + f];
            gh += ak * U.d.sMh[kk * 32 + f];
        }
        z = 1.0f / (1.0f + expf(-z));
        gh = tanhf(gh);
        float h = (1.0f - z) * gh;         // H = (1-Z)*H_tilde (Z*H0 = 0)
        hv[ppp] = h > 0.f ? h : 0.f;       // relu fused
    }
    __syncthreads();
#pragma unroll
    for (int ppp = 0; ppp < 4; ++ppp) {
        int g = (t >> 5) + ppp * 8, f = t & 31;
        U.d.A[g][f] = hv[ppp];
    }
    __syncthreads();

    // logits + softmax16
#pragma unroll
    for (int ppp = 0; ppp < 4; ++ppp) {
        int g = (t >> 5) + ppp * 8, f = t & 31;
        int n2 = blockIdx.x * NPB + g;
        if (f < 16 && n2 < NN) {
            float lg = U.d.sb[f];
#pragma unroll
            for (int jj = 0; jj < 32; ++jj) lg += U.d.A[g][jj] * U.d.sW[jj * 16 + f];
            float mx = lg;
#pragma unroll
            for (int ww = 8; ww >= 1; ww >>= 1) mx = fmaxf(mx, __shfl_xor(mx, ww, 16));
            float pe = expf(lg - mx);
            float sum = pe;
#pragma unroll
            for (int ww = 8; ww >= 1; ww >>= 1) sum += __shfl_xor(sum, ww, 16);
            out[n2 * 16 + f] = pe / sum;
        }
    }
}

extern "C" void kernel_launch(void* const* d_in, const int* in_sizes, int n_in,
                              void* d_out, int out_size, void* d_ws, size_t ws_size,
                              hipStream_t stream) {
    const float* x    = (const float*)d_in[0];
    const int*   ei   = (const int*)d_in[1];
    const float* ew   = (const float*)d_in[2];
    const float* Wz   = (const float*)d_in[3];
    const float* bz   = (const float*)d_in[4];
    // d_in[5..6] (Wr,br), d_in[11..12] (Lr): dead — R gate multiplies H0 = 0.
    const float* Wh   = (const float*)d_in[7];
    const float* bh   = (const float*)d_in[8];
    const float* Lzw  = (const float*)d_in[9];
    const float* Lzb  = (const float*)d_in[10];
    const float* Lhw  = (const float*)d_in[13];
    const float* Lhb  = (const float*)d_in[14];
    const float* Wout = (const float*)d_in[15];
    const float* bout = (const float*)d_in[16];
    float* out = (float*)d_out;

    float* ws = (float*)d_ws;
    float2*   er       = (float2*)ws;                        // NE float2
    float*    dinv     = ws + 2 * (size_t)NE;                // NN
    unsigned* gbincnt8 = (unsigned*)(dinv + NN);             // 8*NBIN
    unsigned* binstart = gbincnt8 + NXCD * NBIN;             // NBIN+1
    unsigned* bincur8  = binstart + NBIN + 1;                // 8*NBIN
    float*    Mz       = (float*)(bincur8 + NXCD * NBIN);    // 1024
    float*    Mh       = Mz + 1024;
    float*    cz       = Mh + 1024;
    float*    chv      = cz + 32;
    __half2*  xh       = (__half2*)(chv + 32);               // NN*16 half2

    k_prep0<<<(NN * 16 + 1023) / 1024, 1024, 0, stream>>>(x, gbincnt8, xh);
    k_cnt<<<WBLK, 256, 0, stream>>>(ei, gbincnt8);
    k_mid<<<2, 256, 0, stream>>>(gbincnt8, binstart, bincur8,
                                 Wz, Lzw, bz, Lzb, Wh, Lhw, bh, Lhb,
                                 Mz, Mh, cz, chv);
    k_binwrite<<<WBLK, 256, 0, stream>>>(ei, ew, bincur8, er);
    k_deg<<<NBIN, 256, 0, stream>>>(er, binstart, dinv);
    k_fused<<<NBIN, 256, 0, stream>>>(er, binstart, dinv, x, xh,
                                      Mz, Mh, cz, chv, Wout, bout, out);
}

// Round 16
// 123.224 us; speedup vs baseline: 1.4941x; 1.4941x over previous
//
#include <hip/hip_runtime.h>
#include <hip/hip_fp16.h>

#define NN 50000
#define NE 1600000
#define NPB 32                       // nodes per bin
#define NBIN ((NN + NPB - 1) / NPB)  // 1563 (last bin: 16 valid nodes)
#define NXCD 8
#define WBLK 512                     // cnt / binwrite chunk blocks
#define EPB (NE / WBLK)              // 3125 edges per chunk
#define CAP 2048                     // staged records per bin (mean 1024, max ~1170)

// ---------------- workspace layout ----------------
// er[NE] float2 {src|(dl<<16), ew}, ordered by (bin, xcd)        12.8 MB
// Aout[NN*32] f32                                                 6.4 MB
// dinv[NN]
// gbincnt8[8*NBIN] u32 (zeroed in k_prep0) : per-(xcd,bin) record counts
// binstart[NBIN+1] u32                     : per-bin global ranges
// bincur8[8*NBIN] u32                      : per-(xcd,bin) write cursors
// Mz[1024] | Mh[1024] | cz[32] | ch[32]
// xh[NN*16] half2 (3.2 MB)                 : fp16 copy of x for the gather
//
// Session ledger (why this exact structure):
//  - direct fp32 atomic scatter: 296 us (r1); atomics cost = memory-side RMW bytes
//  - CSR + padded counters: worse (isolated atomics = 32B sectors, r2/r3)
//  - fp16 accumulation: FAILS accuracy (r4/r11/r12-class errors)
//  - LDS-atomic accumulate: 392-304 us (r5/r6, LDS-atomic serialization)
//  - sort-to-LDS + owner-computes + XCD-private er: 124 us (r7-r10) <= OPTIMUM
//  - cooperative mega-kernel: 499 us (r13, grid.sync + pinned occupancy)
//  - fused dense epilogue: 184 us (r15, VGPR 140 -> occupancy 9.9%)

// Zero counters + convert x -> fp16 rows (halves k_accum's gather bytes).
__global__ __launch_bounds__(1024) void k_prep0(const float* __restrict__ x,
                                                unsigned* __restrict__ gbincnt8,
                                                __half2* __restrict__ xh) {
    int i = blockIdx.x * 1024 + threadIdx.x;
    if (i < NXCD * NBIN) gbincnt8[i] = 0u;
    if (i < NN * 16) {
        float2 v = ((const float2*)x)[i];
        xh[i] = __floats2half2_rn(v.x, v.y);
    }
}

// Per-(xcd,bin) edge counts: LDS histogram per chunk, dense coalesced flush
// into this block's XCD row.
__global__ __launch_bounds__(256) void k_cnt(const int* __restrict__ ei,
                                             unsigned* __restrict__ gbincnt8) {
    __shared__ unsigned cnt[NBIN];
    int t = threadIdx.x;
    int xcd = blockIdx.x & (NXCD - 1);
    for (int i = t; i < NBIN; i += 256) cnt[i] = 0u;
    __syncthreads();
    int lo = blockIdx.x * EPB, hi = lo + EPB;
    for (int e = lo + t; e < hi; e += 256)
        atomicAdd(&cnt[ei[NE + e] >> 5], 1u);              // LDS
    __syncthreads();
    for (int i = t; i < NBIN; i += 256)
        if (cnt[i]) atomicAdd(&gbincnt8[xcd * NBIN + i], cnt[i]);  // coalesced
}

// b==0: scan per-(xcd,bin) counts -> binstart (bin-contiguous) + bincur8
//       (xcd sub-offsets within each bin).
// b==1: fold weights: Mz = Wz@Lzw[:32,:], cz = bz@Lzw + Lzb; same for h.
//       (H0 = 0 kills the R gate and the bottom halves of the gate linears.)
__global__ __launch_bounds__(256) void k_mid(
        const unsigned* __restrict__ gbincnt8, unsigned* __restrict__ binstart,
        unsigned* __restrict__ bincur8,
        const float* __restrict__ Wz, const float* __restrict__ Lzw,
        const float* __restrict__ bz, const float* __restrict__ Lzb,
        const float* __restrict__ Wh, const float* __restrict__ Lhw,
        const float* __restrict__ bh, const float* __restrict__ Lhb,
        float* __restrict__ Mz, float* __restrict__ Mh,
        float* __restrict__ cz, float* __restrict__ chv) {
    int t = threadIdx.x;
    if (blockIdx.x == 0) {
        __shared__ unsigned ts[256];
        unsigned s = 0;
#pragma unroll
        for (int r = 0; r < 7; ++r) {
            int idx = t * 7 + r;
            if (idx < NBIN)
                for (int x = 0; x < NXCD; ++x) s += gbincnt8[x * NBIN + idx];
        }
        ts[t] = s;
        __syncthreads();
        for (int off = 1; off < 256; off <<= 1) {
            unsigned u = (t >= off) ? ts[t - off] : 0u;
            __syncthreads();
            ts[t] += u;
            __syncthreads();
        }
        unsigned acc = (t > 0) ? ts[t - 1] : 0u;
#pragma unroll
        for (int r = 0; r < 7; ++r) {
            int idx = t * 7 + r;
            if (idx < NBIN) {
                binstart[idx] = acc;
                for (int x = 0; x < NXCD; ++x) {
                    bincur8[x * NBIN + idx] = acc;
                    acc += gbincnt8[x * NBIN + idx];
                }
            }
        }
        if (t == 255) binstart[NBIN] = NE;
    } else {
#pragma unroll
        for (int r = 0; r < 4; ++r) {
            int t2 = r * 256 + t;
            int i = t2 >> 5, j = t2 & 31;
            float sz = 0.f, sh = 0.f;
            for (int k = 0; k < 32; ++k) {
                sz += Wz[i * 32 + k] * Lzw[k * 32 + j];
                sh += Wh[i * 32 + k] * Lhw[k * 32 + j];
            }
            Mz[t2] = sz;
            Mh[t2] = sh;
        }
        if (t < 32) {
            float az = Lzb[t], ah = Lhb[t];
            for (int k = 0; k < 32; ++k) {
                az += bz[k] * Lzw[k * 32 + t];
                ah += bh[k] * Lhw[k * 32 + t];
            }
            cz[t] = az;
            chv[t] = ah;
        }
    }
}

// Bin edges by dst into XCD-private sub-ranges: LDS count -> coalesced
// reservation on this XCD's cursor row -> scatter records {src|dl<<16, ew}.
// All stores to any er cache line come from ONE XCD -> full-line write-back.
__global__ __launch_bounds__(256) void k_binwrite(const int* __restrict__ ei,
                                                  const float* __restrict__ ew,
                                                  unsigned* __restrict__ bincur8,
                                                  float2* __restrict__ er) {
    __shared__ unsigned cnt[NBIN], base[NBIN];
    int t = threadIdx.x;
    int xcd = blockIdx.x & (NXCD - 1);
    for (int i = t; i < NBIN; i += 256) cnt[i] = 0u;
    __syncthreads();
    int lo = blockIdx.x * EPB, hi = lo + EPB;
    for (int e = lo + t; e < hi; e += 256)
        atomicAdd(&cnt[ei[NE + e] >> 5], 1u);              // LDS
    __syncthreads();
    for (int i = t; i < NBIN; i += 256)
        base[i] = cnt[i] ? atomicAdd(&bincur8[xcd * NBIN + i], cnt[i]) : 0u;
    __syncthreads();
    for (int e = lo + t; e < hi; e += 256) {
        int s = ei[e], d = ei[NE + e];
        unsigned idx = atomicAdd(&base[d >> 5], 1u);       // LDS cursor
        er[idx] = make_float2(
            __uint_as_float((unsigned)s | ((unsigned)(d & 31) << 16)), ew[e]);
    }
}

// Per-bin in-weight sums from the binned records -> dinv (dense write).
__global__ __launch_bounds__(256) void k_deg(const float2* __restrict__ er,
                                             const unsigned* __restrict__ binstart,
                                             float* __restrict__ dinv) {
    __shared__ float degL[NPB];
    int t = threadIdx.x;
    if (t < NPB) degL[t] = 0.f;
    __syncthreads();
    unsigned beg = binstart[blockIdx.x], end = binstart[blockIdx.x + 1];
    for (unsigned i = beg + t; i < end; i += 256) {
        float2 r = er[i];
        atomicAdd(&degL[(__float_as_uint(r.x) >> 16) & 31u], r.y);  // LDS
    }
    __syncthreads();
    if (t < NPB) {
        int n = blockIdx.x * NPB + t;
        if (n < NN) dinv[n] = rsqrtf(degL[t] + 1.0f);  // +1 = self-loop
    }
}

// One block (256 thr) per bin. Stage records in regs (x dinv[src]) -> per-wave
// hist -> shfl scan -> scatter to SORTED LDS -> owner-computes register
// accumulation (no accumulator atomics). Thread (l = t>>3, j = t&7) owns node
// l's 4-float feature slice; gathers read the fp16 x copy (64B rows).
__global__ __launch_bounds__(256) void k_accum(
        const float2* __restrict__ er, const unsigned* __restrict__ binstart,
        const float* __restrict__ dinv, const float* __restrict__ x,
        const __half2* __restrict__ xh, float* __restrict__ Aout) {
    __shared__ float2 srt[CAP];          // 16 KB
    __shared__ unsigned cnt4[4][32];     // per-wave hist
    __shared__ unsigned base4[4][32];    // scatter cursors
    __shared__ unsigned rowp[33];
    const float4* x4 = (const float4*)x;
    const uint2* xh2 = (const uint2*)xh;  // 4 halves per uint2; 8 per row
    int t = threadIdx.x;
    int w = t >> 6;
    unsigned beg = binstart[blockIdx.x], end = binstart[blockIdx.x + 1];
    unsigned cntb = end - beg;
    unsigned stage = cntb < CAP ? cntb : CAP;

    if (t < 128) ((unsigned*)cnt4)[t] = 0u;
    __syncthreads();

    // stage up to 8 records/thread (weight premultiplied by dinv[src]) + hist
    float2 rec[8];
    unsigned dlk[8];
    bool val[8];
#pragma unroll
    for (int k = 0; k < 8; ++k) {
        unsigned i = (unsigned)t + (unsigned)k * 256u;
        val[k] = (i < stage);
        if (val[k]) {
            float2 r = er[beg + i];
            unsigned pk = __float_as_uint(r.x);
            r.y *= dinv[pk & 0xFFFFu];            // L2-hot 200KB broadcast
            rec[k] = r;
            unsigned d = (pk >> 16) & 31u;
            dlk[k] = d;
            atomicAdd(&cnt4[w][d], 1u);           // within-wave collisions only
        }
    }
    __syncthreads();

    // lanes 0..31 of wave 0: per-node totals, exclusive scan, per-wave bases
    if (t < 32) {
        unsigned s = 0;
#pragma unroll
        for (int ww = 0; ww < 4; ++ww) {
            unsigned c = cnt4[ww][t];
            base4[ww][t] = s;
            s += c;
        }
        unsigned tot = s;
#pragma unroll
        for (int off = 1; off < 32; off <<= 1) {
            unsigned v = __shfl_up(tot, off, 32);
            if (t >= off) tot += v;
        }
        unsigned excl = tot - s;
        rowp[t] = excl;
        if (t == 31) rowp[32] = excl + s;
#pragma unroll
        for (int ww = 0; ww < 4; ++ww) base4[ww][t] += excl;
    }
    __syncthreads();

    // scatter to sorted LDS
#pragma unroll
    for (int k = 0; k < 8; ++k) {
        if (val[k]) {
            unsigned p = atomicAdd(&base4[w][dlk[k]], 1u);
            srt[p] = rec[k];
        }
    }
    __syncthreads();

    // owner-computes: node l, 4-float slice j. Register accumulation; fp16
    // gathers (8B per record instead of 16B), fp32 math.
    int l = t >> 3, j = t & 7;
    int n = blockIdx.x * NPB + l;
    float4 acc = make_float4(0.f, 0.f, 0.f, 0.f);
    unsigned rb = rowp[l], re = rowp[l + 1];
    unsigned i = rb;
    for (; i + 4 <= re; i += 4) {
        float2 r0 = srt[i], r1 = srt[i + 1], r2 = srt[i + 2], r3 = srt[i + 3];
        unsigned s0 = __float_as_uint(r0.x) & 0xFFFFu;
        unsigned s1 = __float_as_uint(r1.x) & 0xFFFFu;
        unsigned s2 = __float_as_uint(r2.x) & 0xFFFFu;
        unsigned s3 = __float_as_uint(r3.x) & 0xFFFFu;
        uint2 v0 = xh2[s0 * 8 + j];
        uint2 v1 = xh2[s1 * 8 + j];
        uint2 v2 = xh2[s2 * 8 + j];
        uint2 v3 = xh2[s3 * 8 + j];
        float2 a0 = __half22float2(*(const __half2*)&v0.x);
        float2 b0 = __half22float2(*(const __half2*)&v0.y);
        float2 a1 = __half22float2(*(const __half2*)&v1.x);
        float2 b1 = __half22float2(*(const __half2*)&v1.y);
        float2 a2 = __half22float2(*(const __half2*)&v2.x);
        float2 b2 = __half22float2(*(const __half2*)&v2.y);
        float2 a3 = __half22float2(*(const __half2*)&v3.x);
        float2 b3 = __half22float2(*(const __half2*)&v3.y);
        acc.x += r0.y * a0.x; acc.y += r0.y * a0.y; acc.z += r0.y * b0.x; acc.w += r0.y * b0.y;
        acc.x += r1.y * a1.x; acc.y += r1.y * a1.y; acc.z += r1.y * b1.x; acc.w += r1.y * b1.y;
        acc.x += r2.y * a2.x; acc.y += r2.y * a2.y; acc.z += r2.y * b2.x; acc.w += r2.y * b2.y;
        acc.x += r3.y * a3.x; acc.y += r3.y * a3.y; acc.z += r3.y * b3.x; acc.w += r3.y * b3.y;
    }
    for (; i < re; ++i) {
        float2 r = srt[i];
        unsigned s = __float_as_uint(r.x) & 0xFFFFu;
        uint2 v = xh2[s * 8 + j];
        float2 a = __half22float2(*(const __half2*)&v.x);
        float2 b = __half22float2(*(const __half2*)&v.y);
        acc.x += r.y * a.x; acc.y += r.y * a.y; acc.z += r.y * b.x; acc.w += r.y * b.y;
    }
    // overflow fallback (never triggers for this input: max bin ~1170 < 2048)
    for (unsigned o = stage; o < cntb; ++o) {
        float2 r = er[beg + o];
        unsigned pk = __float_as_uint(r.x);
        if (((pk >> 16) & 31u) == (unsigned)l) {
            unsigned s = pk & 0xFFFFu;
            uint2 v = xh2[s * 8 + j];
            float2 a = __half22float2(*(const __half2*)&v.x);
            float2 b = __half22float2(*(const __half2*)&v.y);
            float vv = r.y * dinv[s];
            acc.x += vv * a.x; acc.y += vv * a.y; acc.z += vv * b.x; acc.w += vv * b.y;
        }
    }
    if (n < NN) {
        float dv = dinv[n];
        float4 xv = x4[n * 8 + j];      // self-loop term from fp32 x (exact)
        float4 o;
        o.x = dv * (acc.x + dv * xv.x);
        o.y = dv * (acc.y + dv * xv.y);
        o.z = dv * (acc.z + dv * xv.z);
        o.w = dv * (acc.w + dv * xv.w);
        ((float4*)Aout)[n * 8 + j] = o;
    }
}

// Dense epilogue: gates + relu + 32x16 matvec + softmax16. 32 lanes = 1 node.
__global__ __launch_bounds__(256) void k_dense(
        const float* __restrict__ Aout, const float* __restrict__ Mz,
        const float* __restrict__ Mh, const float* __restrict__ cz,
        const float* __restrict__ chv, const float* __restrict__ Wout,
        const float* __restrict__ bout, float* __restrict__ out) {
    __shared__ float sMz[1024], sMh[1024], sW[512], scz[32], sch[32], sb[16];
    __shared__ float sA[8][32];
    int tid = threadIdx.x;
    for (int i = tid; i < 1024; i += 256) { sMz[i] = Mz[i]; sMh[i] = Mh[i]; }
    for (int i = tid; i < 512; i += 256) sW[i] = Wout[i];
    if (tid < 32) { scz[tid] = cz[tid]; sch[tid] = chv[tid]; }
    if (tid < 16) sb[tid] = bout[tid];

    int g = tid >> 5, f = tid & 31;
    int n = blockIdx.x * 8 + g;
    float av = Aout[(size_t)n * 32 + f];
    sA[g][f] = av;
    __syncthreads();

    float z = scz[f], gh = sch[f];
#pragma unroll
    for (int k = 0; k < 32; ++k) {
        float ak = sA[g][k];
        z += ak * sMz[k * 32 + f];
        gh += ak * sMh[k * 32 + f];
    }
    z = 1.0f / (1.0f + expf(-z));
    gh = tanhf(gh);
    float hv = (1.0f - z) * gh;      // H = (1-Z)*H_tilde  (Z*H0 = 0)
    hv = hv > 0.f ? hv : 0.f;        // relu fused
    __syncthreads();
    sA[g][f] = hv;
    __syncthreads();

    if (f < 16) {
        float lg = sb[f];
#pragma unroll
        for (int j = 0; j < 32; ++j) lg += sA[g][j] * sW[j * 16 + f];
        float mx = lg;
#pragma unroll
        for (int w = 8; w >= 1; w >>= 1) mx = fmaxf(mx, __shfl_xor(mx, w, 16));
        float p = expf(lg - mx);
        float sum = p;
#pragma unroll
        for (int w = 8; w >= 1; w >>= 1) sum += __shfl_xor(sum, w, 16);
        out[n * 16 + f] = p / sum;
    }
}

extern "C" void kernel_launch(void* const* d_in, const int* in_sizes, int n_in,
                              void* d_out, int out_size, void* d_ws, size_t ws_size,
                              hipStream_t stream) {
    const float* x    = (const float*)d_in[0];
    const int*   ei   = (const int*)d_in[1];
    const float* ew   = (const float*)d_in[2];
    const float* Wz   = (const float*)d_in[3];
    const float* bz   = (const float*)d_in[4];
    // d_in[5..6] (Wr,br), d_in[11..12] (Lr): dead — R gate multiplies H0 = 0.
    const float* Wh   = (const float*)d_in[7];
    const float* bh   = (const float*)d_in[8];
    const float* Lzw  = (const float*)d_in[9];
    const float* Lzb  = (const float*)d_in[10];
    const float* Lhw  = (const float*)d_in[13];
    const float* Lhb  = (const float*)d_in[14];
    const float* Wout = (const float*)d_in[15];
    const float* bout = (const float*)d_in[16];
    float* out = (float*)d_out;

    float* ws = (float*)d_ws;
    float2*   er       = (float2*)ws;                        // NE float2
    float*    Aout     = ws + 2 * (size_t)NE;                // NN*32
    float*    dinv     = Aout + (size_t)NN * 32;             // NN
    unsigned* gbincnt8 = (unsigned*)(dinv + NN);             // 8*NBIN
    unsigned* binstart = gbincnt8 + NXCD * NBIN;             // NBIN+1
    unsigned* bincur8  = binstart + NBIN + 1;                // 8*NBIN
    float*    Mz       = (float*)(bincur8 + NXCD * NBIN);    // 1024
    float*    Mh       = Mz + 1024;
    float*    cz       = Mh + 1024;
    float*    chv      = cz + 32;
    __half2*  xh       = (__half2*)(chv + 32);               // NN*16 half2

    k_prep0<<<(NN * 16 + 1023) / 1024, 1024, 0, stream>>>(x, gbincnt8, xh);
    k_cnt<<<WBLK, 256, 0, stream>>>(ei, gbincnt8);
    k_mid<<<2, 256, 0, stream>>>(gbincnt8, binstart, bincur8,
                                 Wz, Lzw, bz, Lzb, Wh, Lhw, bh, Lhb,
                                 Mz, Mh, cz, chv);
    k_binwrite<<<WBLK, 256, 0, stream>>>(ei, ew, bincur8, er);
    k_deg<<<NBIN, 256, 0, stream>>>(er, binstart, dinv);
    k_accum<<<NBIN, 256, 0, stream>>>(er, binstart, dinv, x, xh, Aout);
    k_dense<<<NN / 8, 256, 0, stream>>>(Aout, Mz, Mh, cz, chv, Wout, bout, out);
}